// Round 9
// baseline (786.479 us; speedup 1.0000x reference)
//
#include <hip/hip_runtime.h>
#include <hip/hip_cooperative_groups.h>

namespace cg = cooperative_groups;

#define M_VERT 32768
#define NBATCH 8
#define FIN 32
#define RANK 5
#define FILT 32
#define E_NNZ 262144
#define ROWLEN 256                    // NBATCH*FIN elements per vertex row
#define EVROW 40                      // fixed ev slots per row (P(cnt>40) ~ 1e-16), mult of 8

typedef short short8 __attribute__((ext_vector_type(8)));
typedef float f32x4 __attribute__((ext_vector_type(4)));

__device__ __forceinline__ float bfl(unsigned int u) {           // low bf16 -> f32
    unsigned int x = u << 16; return __builtin_bit_cast(float, x);
}
__device__ __forceinline__ float bfh(unsigned int u) {           // high bf16 -> f32
    unsigned int x = u & 0xffff0000u; return __builtin_bit_cast(float, x);
}
__device__ __forceinline__ unsigned int f2bf(float f) {          // f32 -> bf16 (RNE)
    unsigned int x = __builtin_bit_cast(unsigned int, f);
    return (x + 0x7fffu + ((x >> 16) & 1u)) >> 16;
}
__device__ __forceinline__ unsigned int pk(float a, float b) {
    return f2bf(a) | (f2bf(b) << 16);
}

// ================= phase bodies (bit-identical math to the R6 kernels) =================
// All take G = number of real blocks and grid-stride over their virtual work.

// pack x [N,M,Fin] fp32 -> T0 [m][n*32+fin] bf16; + edge scatter into fixed-stride ev
// (fill atomic doubles as histogram; no prefix scan); + packw MFMA B-fragments.
__device__ __forceinline__ void pack_body(int G, const float* __restrict__ x,
                                          unsigned short* __restrict__ T0,
                                          const int* __restrict__ rows,
                                          const int* __restrict__ cols,
                                          const float* __restrict__ vals,
                                          int* __restrict__ fill, int2* __restrict__ ev,
                                          const float* __restrict__ W,
                                          unsigned short* __restrict__ Wb) {
    for (int tid = blockIdx.x * 256 + threadIdx.x; tid < M_VERT * 32; tid += G * 256) {
        int m = tid >> 5;
        int r = tid & 31;
        int n = r >> 2;
        int q = r & 3;
        const float* src = x + ((size_t)n * M_VERT + m) * FIN + q * 8;
        float4 v0 = *(const float4*)(src);
        float4 v1 = *(const float4*)(src + 4);
        uint4 u;
        u.x = pk(v0.x, v0.y); u.y = pk(v0.z, v0.w);
        u.z = pk(v1.x, v1.y); u.w = pk(v1.z, v1.w);
        *(uint4*)(T0 + (size_t)m * ROWLEN + n * FIN + q * 8) = u;

        if (tid < E_NNZ) {
            int rr = rows[tid];
            int pos = atomicAdd(&fill[rr], 1);
            if (pos < EVROW) {                   // safety clamp (never taken in practice)
                int2 p; p.x = cols[tid]; p.y = __builtin_bit_cast(int, vals[tid]);
                ev[rr * EVROW + pos] = p;
            }
        }

        if (tid < 640) {
            int lane = tid & 63;
            int kf = tid >> 6;
            int k = kf >> 1, ft = kf & 1;
            int f = ft * 16 + (lane & 15);
            int fin0 = (lane >> 4) * 8;
            unsigned short tmp[8];
#pragma unroll
            for (int j = 0; j < 8; ++j)
                tmp[j] = (unsigned short)f2bf(W[((fin0 + j) * RANK + k) * FILT + f]);
            uint4 uw;
            uw.x = (unsigned int)tmp[0] | ((unsigned int)tmp[1] << 16);
            uw.y = (unsigned int)tmp[2] | ((unsigned int)tmp[3] << 16);
            uw.z = (unsigned int)tmp[4] | ((unsigned int)tmp[5] << 16);
            uw.w = (unsigned int)tmp[6] | ((unsigned int)tmp[7] << 16);
            *(uint4*)(Wb + (size_t)tid * 8) = uw;
        }
    }
}

// SpMM: one wave per vertex, uniform row bounds (readfirstlane), 8-unrolled edge
// stream -> 8 outstanding coalesced 512B gathers; pads zeroed in ev (exact 0).
// Tsub nt (pure stream); Tout cached (next step's gather target). R6-proven 29 us.
__device__ __forceinline__ void spmm_body(int G, const int* __restrict__ cnt,
                                          const unsigned long long* __restrict__ ev,
                                          const unsigned short* __restrict__ Tin,
                                          const unsigned short* __restrict__ Tsub,
                                          unsigned short* __restrict__ Tout, int cheb) {
    int w = threadIdx.x >> 6;
    int l = threadIdx.x & 63;
    unsigned int coff = (unsigned int)l * 8u;    // byte offset within 512B row
    const char* tb = (const char*)Tin;
    for (int bv = blockIdx.x; bv < M_VERT / 4; bv += G) {
        int m = bv * 4 + w;
        int c = __builtin_amdgcn_readfirstlane(cnt[m]);
        int cp = (c + 7) & ~7;                   // pad to multiple of 8
        if (cp > EVROW) cp = EVROW;              // matches scatter clamp
        int s = m * EVROW;
        int e = s + cp;
        float a0 = 0.f, a1 = 0.f, a2 = 0.f, a3 = 0.f;
        for (int j = s; j < e; j += 8) {
            unsigned long long ed[8];
#pragma unroll
            for (int i = 0; i < 8; ++i) ed[i] = ev[j + i];   // uniform -> scalar loads
            uint2 t[8];
#pragma unroll
            for (int i = 0; i < 8; ++i)
                t[i] = *(const uint2*)(tb + (((unsigned int)ed[i]) << 9) + coff);
#pragma unroll
            for (int i = 0; i < 8; ++i) {
                float v = __builtin_bit_cast(float, (unsigned int)(ed[i] >> 32));
                a0 += v * bfl(t[i].x); a1 += v * bfh(t[i].x);
                a2 += v * bfl(t[i].y); a3 += v * bfh(t[i].y);
            }
        }
        size_t moff = (size_t)m * 512 + coff;
        if (cheb) {
            unsigned long long o = __builtin_nontemporal_load(
                (const unsigned long long*)((const char*)Tsub + moff));
            unsigned int ox = (unsigned int)o, oy = (unsigned int)(o >> 32);
            a0 = 2.f * a0 - bfl(ox); a1 = 2.f * a1 - bfh(ox);
            a2 = 2.f * a2 - bfl(oy); a3 = 2.f * a3 - bfh(oy);
        }
        uint2 rr;
        rr.x = pk(a0, a1); rr.y = pk(a2, a3);
        *(uint2*)((char*)Tout + moff) = rr;
    }
}

// GEMM: out[n,m,f] = bias[f] + sum_k T_k[m, n*32+:] @ W_k; MFMA 16x16x32 bf16.
// bfrag/bias hoisted outside the virtual-block loop (lane-only dependent).
__device__ __forceinline__ void gemm_body(int G,
                                          const unsigned short* __restrict__ T0,
                                          const unsigned short* __restrict__ T1,
                                          const unsigned short* __restrict__ T2,
                                          const unsigned short* __restrict__ T3,
                                          const unsigned short* __restrict__ T4,
                                          const unsigned short* __restrict__ Wb,
                                          const float* __restrict__ bias,
                                          float* __restrict__ out) {
    int w = threadIdx.x >> 6;
    int l = threadIdx.x & 63;
    int lrow = l & 15;           // A's m-offset AND C's column f
    int quad = l >> 4;

    short8 bfrag[5][2];
#pragma unroll
    for (int kf = 0; kf < 10; ++kf)
        bfrag[kf >> 1][kf & 1] = *(const short8*)(Wb + ((size_t)kf * 64 + l) * 8);
    float b0 = bias[lrow];
    float b1 = bias[16 + lrow];
    const unsigned short* Ts[5] = {T0, T1, T2, T3, T4};

    for (int bv = blockIdx.x; bv < (M_VERT / 64) * 8; bv += G) {
        int n  = bv & 7;
        int mb = bv >> 3;
        int m0 = (mb * 4 + w) * 16;
        size_t abase = (size_t)(m0 + lrow) * ROWLEN + quad * 8 + n * FIN;
        f32x4 c0 = {0.f, 0.f, 0.f, 0.f};
        f32x4 c1 = {0.f, 0.f, 0.f, 0.f};
#pragma unroll
        for (int k = 0; k < 5; ++k) {
            short8 a = *(const short8*)(Ts[k] + abase);
            c0 = __builtin_amdgcn_mfma_f32_16x16x32_bf16(a, bfrag[k][0], c0, 0, 0, 0);
            c1 = __builtin_amdgcn_mfma_f32_16x16x32_bf16(a, bfrag[k][1], c1, 0, 0, 0);
        }
        float* op = out + ((size_t)n * M_VERT + m0) * FILT;
#pragma unroll
        for (int r = 0; r < 4; ++r) {
            int orow = quad * 4 + r;
            __builtin_nontemporal_store(c0[r] + b0, &op[(size_t)orow * FILT + lrow]);
            __builtin_nontemporal_store(c1[r] + b1, &op[(size_t)orow * FILT + 16 + lrow]);
        }
    }
}

// ================= single cooperative kernel: all phases, 6 grid syncs =================
// Replaces 8 dispatches (7 x ~10us launch gaps, measured via R4->R6 delta) with
// 6 in-kernel grid barriers (~3-6us each). Phase bodies identical to the verified
// R6 kernels; grid sized by occupancy query -> co-residency guaranteed.

__global__ __launch_bounds__(256) void fused_kernel(const float* __restrict__ x,
                                                    const int* __restrict__ rows,
                                                    const int* __restrict__ cols,
                                                    const float* __restrict__ vals,
                                                    const float* __restrict__ W,
                                                    const float* __restrict__ bias,
                                                    float* __restrict__ out,
                                                    unsigned short* T0, unsigned short* T1,
                                                    unsigned short* T2, unsigned short* T3,
                                                    unsigned short* T4,
                                                    int* fill, int2* ev,
                                                    unsigned short* Wb) {
    cg::grid_group grid = cg::this_grid();
    const int G = gridDim.x;

    // phase 0: zero fill + ev (contiguous region, 16B vectors)
    {
        int4* z = (int4*)fill;                   // ev immediately follows fill in ws
        const int total = (M_VERT * 4 + M_VERT * EVROW * 8) / 16;
        int4 zero = {0, 0, 0, 0};
        for (int i = blockIdx.x * 256 + threadIdx.x; i < total; i += G * 256)
            z[i] = zero;
    }
    grid.sync();

    // phase 1: pack + edge scatter + packw
    pack_body(G, x, T0, rows, cols, vals, fill, ev, W, Wb);
    grid.sync();

    // phases 2-5: Chebyshev recurrence (all T_k kept, bf16)
    const unsigned long long* evq = (const unsigned long long*)ev;
    spmm_body(G, fill, evq, T0, T0, T1, 0); grid.sync();
    spmm_body(G, fill, evq, T1, T0, T2, 1); grid.sync();
    spmm_body(G, fill, evq, T2, T1, T3, 1); grid.sync();
    spmm_body(G, fill, evq, T3, T2, T4, 1); grid.sync();

    // phase 6: fused epilogue GEMM
    gemm_body(G, T0, T1, T2, T3, T4, Wb, bias, out);
}

// ================= fallback wrappers (exact R6 path; same device bodies) =================

__global__ __launch_bounds__(256) void pack_kernel(const float* __restrict__ x,
                                                   unsigned short* __restrict__ T0,
                                                   const int* __restrict__ rows,
                                                   const int* __restrict__ cols,
                                                   const float* __restrict__ vals,
                                                   int* __restrict__ fill,
                                                   int2* __restrict__ ev,
                                                   const float* __restrict__ W,
                                                   unsigned short* __restrict__ Wb) {
    pack_body(gridDim.x, x, T0, rows, cols, vals, fill, ev, W, Wb);
}

__global__ __launch_bounds__(256) void spmm_kernel(const int* __restrict__ cnt,
                                                   const unsigned long long* __restrict__ ev,
                                                   const unsigned short* __restrict__ Tin,
                                                   const unsigned short* __restrict__ Tsub,
                                                   unsigned short* __restrict__ Tout, int cheb) {
    spmm_body(gridDim.x, cnt, ev, Tin, Tsub, Tout, cheb);
}

__global__ __launch_bounds__(256) void gemm_kernel(const unsigned short* __restrict__ T0,
                                                   const unsigned short* __restrict__ T1,
                                                   const unsigned short* __restrict__ T2,
                                                   const unsigned short* __restrict__ T3,
                                                   const unsigned short* __restrict__ T4,
                                                   const unsigned short* __restrict__ Wb,
                                                   const float* __restrict__ bias,
                                                   float* __restrict__ out) {
    gemm_body(gridDim.x, T0, T1, T2, T3, T4, Wb, bias, out);
}

// ---------------- launch ----------------

extern "C" void kernel_launch(void* const* d_in, const int* in_sizes, int n_in,
                              void* d_out, int out_size, void* d_ws, size_t ws_size,
                              hipStream_t stream) {
    const float* x    = (const float*)d_in[0];
    const float* vals = (const float*)d_in[1];
    const float* W    = (const float*)d_in[2];
    const float* bias = (const float*)d_in[3];
    const int*   rows = (const int*)d_in[4];
    const int*   cols = (const int*)d_in[5];
    float* out = (float*)d_out;

    // workspace: 5 bf16 T buffers (16 MiB each) + fill + fixed-stride ev + Wb
    const size_t TSZ = (size_t)M_VERT * ROWLEN;
    unsigned short* T0 = (unsigned short*)d_ws;
    unsigned short* T1 = T0 + TSZ;
    unsigned short* T2 = T1 + TSZ;
    unsigned short* T3 = T2 + TSZ;
    unsigned short* T4 = T3 + TSZ;
    int*  fill = (int*)(T4 + TSZ);               // fill then ev: one contiguous zero region
    int2* ev   = (int2*)(fill + M_VERT);
    unsigned short* Wb = (unsigned short*)(ev + (size_t)M_VERT * EVROW);

    // grid size: co-resident blocks only (cooperative requirement); cap at 6/CU
    static int blocksPerCU = 0;
    if (blocksPerCU == 0) {
        int nb = 0;
        hipError_t qe = hipOccupancyMaxActiveBlocksPerMultiprocessor(
            &nb, (const void*)fused_kernel, 256, 0);
        blocksPerCU = (qe == hipSuccess && nb > 0) ? nb : -1;
    }

    bool launched = false;
    if (blocksPerCU > 0) {
        int bpc = blocksPerCU > 6 ? 6 : blocksPerCU;
        dim3 grid(bpc * 256), block(256);
        void* args[] = {(void*)&x, (void*)&rows, (void*)&cols, (void*)&vals,
                        (void*)&W, (void*)&bias, (void*)&out,
                        (void*)&T0, (void*)&T1, (void*)&T2, (void*)&T3, (void*)&T4,
                        (void*)&fill, (void*)&ev, (void*)&Wb};
        hipError_t le = hipLaunchCooperativeKernel((const void*)fused_kernel,
                                                   grid, block, args, 0, stream);
        launched = (le == hipSuccess);
    }

    if (!launched) {
        // fallback: verified R6 8-dispatch path (same device bodies)
        hipMemsetAsync(fill, 0, M_VERT * sizeof(int), stream);
        hipMemsetAsync(ev, 0, (size_t)M_VERT * EVROW * sizeof(int2), stream);
        pack_kernel<<<M_VERT * 32 / 256, 256, 0, stream>>>(x, T0, rows, cols, vals,
                                                           fill, ev, W, Wb);
        const unsigned long long* evq = (const unsigned long long*)ev;
        spmm_kernel<<<M_VERT / 4, 256, 0, stream>>>(fill, evq, T0, T0, T1, 0);
        spmm_kernel<<<M_VERT / 4, 256, 0, stream>>>(fill, evq, T1, T0, T2, 1);
        spmm_kernel<<<M_VERT / 4, 256, 0, stream>>>(fill, evq, T2, T1, T3, 1);
        spmm_kernel<<<M_VERT / 4, 256, 0, stream>>>(fill, evq, T3, T2, T4, 1);
        gemm_kernel<<<(M_VERT / 64) * 8, 256, 0, stream>>>(T0, T1, T2, T3, T4, Wb, bias, out);
    }
}

// Round 10
// 228.379 us; speedup vs baseline: 3.4437x; 3.4437x over previous
//
#include <hip/hip_runtime.h>

#define M_VERT 32768
#define NBATCH 8
#define FIN 32
#define RANK 5
#define FILT 32
#define E_NNZ 262144
#define ROWLEN 256                    // NBATCH*FIN elements per vertex row
#define EVROW 40                      // fixed ev slots per row (P(cnt>40) ~ 1e-16), mult of 8

typedef short short8 __attribute__((ext_vector_type(8)));
typedef float f32x4 __attribute__((ext_vector_type(4)));
typedef unsigned long long u64;

__device__ __forceinline__ float bfl(unsigned int u) {           // low bf16 -> f32
    unsigned int x = u << 16; return __builtin_bit_cast(float, x);
}
__device__ __forceinline__ float bfh(unsigned int u) {           // high bf16 -> f32
    unsigned int x = u & 0xffff0000u; return __builtin_bit_cast(float, x);
}
__device__ __forceinline__ unsigned int f2bf(float f) {          // f32 -> bf16 (RNE)
    unsigned int x = __builtin_bit_cast(unsigned int, f);
    return (x + 0x7fffu + ((x >> 16) & 1u)) >> 16;
}
__device__ __forceinline__ unsigned int pk(float a, float b) {
    return f2bf(a) | (f2bf(b) << 16);
}

// ---------------- pack x -> T0 bf16 + CSR build + packw (R6-proven) ----------------
// pack: [N,M,Fin] fp32 -> T0 [m][n*32+fin] bf16 (M*32 threads, 8 elems each).
// CSR: fixed-stride ev (EVROW slots/row); slot from the fill atomic (doubles as
// histogram) -- no scan, no scatter dispatch. ev pads are NOT zeroed anymore:
// the spmm masks its tail instead (saves the 3.3 MB ev memset + a launch gap).
// packw: first 640 threads pack W into the MFMA B-fragment layout.

__global__ void pack_kernel(const float* __restrict__ x, unsigned short* __restrict__ T0,
                            const int* __restrict__ rows, const int* __restrict__ cols,
                            const float* __restrict__ vals,
                            int* __restrict__ fill, int2* __restrict__ ev,
                            const float* __restrict__ W, unsigned short* __restrict__ Wb) {
    int tid = blockIdx.x * blockDim.x + threadIdx.x;   // M*32 threads
    int m = tid >> 5;
    int r = tid & 31;
    int n = r >> 2;
    int q = r & 3;
    const float* src = x + ((size_t)n * M_VERT + m) * FIN + q * 8;
    float4 v0 = *(const float4*)(src);
    float4 v1 = *(const float4*)(src + 4);
    uint4 u;
    u.x = pk(v0.x, v0.y); u.y = pk(v0.z, v0.w);
    u.z = pk(v1.x, v1.y); u.w = pk(v1.z, v1.w);
    *(uint4*)(T0 + (size_t)m * ROWLEN + n * FIN + q * 8) = u;

    if (tid < E_NNZ) {
        int rr = rows[tid];
        int pos = atomicAdd(&fill[rr], 1);
        if (pos < EVROW) {                       // safety clamp (never taken in practice)
            int2 p; p.x = cols[tid]; p.y = __builtin_bit_cast(int, vals[tid]);
            ev[rr * EVROW + pos] = p;
        }
    }

    if (tid < 640) {
        int lane = tid & 63;
        int kf = tid >> 6;
        int k = kf >> 1, ft = kf & 1;
        int f = ft * 16 + (lane & 15);
        int fin0 = (lane >> 4) * 8;
        unsigned short tmp[8];
#pragma unroll
        for (int j = 0; j < 8; ++j)
            tmp[j] = (unsigned short)f2bf(W[((fin0 + j) * RANK + k) * FILT + f]);
        uint4 uw;
        uw.x = (unsigned int)tmp[0] | ((unsigned int)tmp[1] << 16);
        uw.y = (unsigned int)tmp[2] | ((unsigned int)tmp[3] << 16);
        uw.z = (unsigned int)tmp[4] | ((unsigned int)tmp[5] << 16);
        uw.w = (unsigned int)tmp[6] | ((unsigned int)tmp[7] << 16);
        *(uint4*)(Wb + (size_t)tid * 8) = uw;
    }
}

// ---------------- SpMM (bf16): Tout = L*Tin  or  2*L*Tin - Tsub ----------------
// R6-proven: one wave per vertex; uniform bounds via readfirstlane -> scalar ev
// loads; 64 lanes gather the SAME row -> one coalesced 512B transaction per edge;
// 8 outstanding gathers. Tail (<8 edges) is MASKED: col/val forced to 0 before
// the gather (col 0 -> vertex-0 hot line, val 0 -> exact zero term), so ev pad
// slots may hold garbage safely -> no ev memset dispatch needed.
// Tsub nt (pure stream); Tout cached (next step's gather target).

__global__ __launch_bounds__(256) void spmm_kernel(const int* __restrict__ cnt,
                                                   const u64* __restrict__ ev,
                                                   const unsigned short* __restrict__ Tin,
                                                   const unsigned short* __restrict__ Tsub,
                                                   unsigned short* __restrict__ Tout, int cheb) {
    int w = threadIdx.x >> 6;
    int l = threadIdx.x & 63;
    int m = blockIdx.x * 4 + w;
    unsigned int coff = (unsigned int)l * 8u;    // byte offset within 512B row
    int c = __builtin_amdgcn_readfirstlane(cnt[m]);
    if (c > EVROW) c = EVROW;                    // matches scatter clamp
    int s = m * EVROW;
    int cf = c & ~7;
    const char* tb = (const char*)Tin;
    float a0 = 0.f, a1 = 0.f, a2 = 0.f, a3 = 0.f;
    int j = 0;
    for (; j < cf; j += 8) {                     // full 8-packs (no predication)
        u64 ed[8];
#pragma unroll
        for (int i = 0; i < 8; ++i) ed[i] = ev[s + j + i];   // uniform -> scalar loads
        uint2 t[8];
#pragma unroll
        for (int i = 0; i < 8; ++i)
            t[i] = *(const uint2*)(tb + (((unsigned int)ed[i]) << 9) + coff);
#pragma unroll
        for (int i = 0; i < 8; ++i) {
            float v = __builtin_bit_cast(float, (unsigned int)(ed[i] >> 32));
            a0 += v * bfl(t[i].x); a1 += v * bfh(t[i].x);
            a2 += v * bfl(t[i].y); a3 += v * bfh(t[i].y);
        }
    }
    if (j < c) {                                 // masked tail (1..7 real edges)
        int rem = c - j;
        u64 ed[8];
#pragma unroll
        for (int i = 0; i < 8; ++i) ed[i] = ev[s + j + i];   // may read garbage pads
        unsigned int cm[8]; float vm[8];
#pragma unroll
        for (int i = 0; i < 8; ++i) {            // mask BEFORE any deref
            bool ok = i < rem;
            cm[i] = ok ? (unsigned int)ed[i] : 0u;
            vm[i] = ok ? __builtin_bit_cast(float, (unsigned int)(ed[i] >> 32)) : 0.f;
        }
        uint2 t[8];
#pragma unroll
        for (int i = 0; i < 8; ++i)
            t[i] = *(const uint2*)(tb + (cm[i] << 9) + coff);
#pragma unroll
        for (int i = 0; i < 8; ++i) {
            a0 += vm[i] * bfl(t[i].x); a1 += vm[i] * bfh(t[i].x);
            a2 += vm[i] * bfl(t[i].y); a3 += vm[i] * bfh(t[i].y);
        }
    }
    size_t moff = (size_t)m * 512 + coff;
    if (cheb) {
        u64 o = __builtin_nontemporal_load((const u64*)((const char*)Tsub + moff));
        unsigned int ox = (unsigned int)o, oy = (unsigned int)(o >> 32);
        a0 = 2.f * a0 - bfl(ox); a1 = 2.f * a1 - bfh(ox);
        a2 = 2.f * a2 - bfl(oy); a3 = 2.f * a3 - bfh(oy);
    }
    uint2 rr;
    rr.x = pk(a0, a1); rr.y = pk(a2, a3);
    *(uint2*)((char*)Tout + moff) = rr;
}

// ---------------- fused final SpMM + GEMM ----------------
// Block = 1024 threads (16 waves) owns 64 vertices. Phase A: wave w computes
// T4 rows w*4..w*4+3 (identical structure/TLP to spmm_kernel: 32 waves/CU, one
// vertex per wave-iteration, 8 outstanding 512B gathers) and writes them to LDS
// (XOR-swizzled: byte ^ ((row&7)<<4) -> the gemm's stride-512 reads spread
// across banks instead of a 16-way conflict, G4). Phase B after __syncthreads:
// MFMA gemm for these 64 rows x all 8 batch slices; A k=0..3 from global,
// k=4 from LDS. T4 NEVER touches global memory (-16MB write, -16MB read,
// -1 dispatch, -1 gap). Wb re-loaded per k (tiny, L2-hot) to keep VGPR<=64 so
// 2 blocks/CU co-reside (512 blocks = exactly 2/CU).

__global__ __launch_bounds__(1024, 8) void spmm4_gemm_kernel(
        const int* __restrict__ cnt, const u64* __restrict__ ev,
        const unsigned short* __restrict__ T0, const unsigned short* __restrict__ T1,
        const unsigned short* __restrict__ T2, const unsigned short* __restrict__ T3,
        const unsigned short* __restrict__ Wb, const float* __restrict__ bias,
        float* __restrict__ out) {
    __shared__ unsigned short sT4[64 * 256];     // 32 KB
    int w = threadIdx.x >> 6;                    // wave 0..15
    int l = threadIdx.x & 63;
    int mb0 = blockIdx.x * 64;
    unsigned int coff = (unsigned int)l * 8u;
    const char* tb = (const char*)T3;            // Tin = T3

    // ---- phase A: T4 rows = 2*L*T3 - T2 -> LDS (swizzled) ----
    for (int vi = 0; vi < 4; ++vi) {
        int lr = w * 4 + vi;                     // local row 0..63
        int m = mb0 + lr;
        int c = __builtin_amdgcn_readfirstlane(cnt[m]);
        if (c > EVROW) c = EVROW;
        int s = m * EVROW;
        int cf = c & ~7;
        float a0 = 0.f, a1 = 0.f, a2 = 0.f, a3 = 0.f;
        int j = 0;
        for (; j < cf; j += 8) {
            u64 ed[8];
#pragma unroll
            for (int i = 0; i < 8; ++i) ed[i] = ev[s + j + i];
            uint2 t[8];
#pragma unroll
            for (int i = 0; i < 8; ++i)
                t[i] = *(const uint2*)(tb + (((unsigned int)ed[i]) << 9) + coff);
#pragma unroll
            for (int i = 0; i < 8; ++i) {
                float v = __builtin_bit_cast(float, (unsigned int)(ed[i] >> 32));
                a0 += v * bfl(t[i].x); a1 += v * bfh(t[i].x);
                a2 += v * bfl(t[i].y); a3 += v * bfh(t[i].y);
            }
        }
        if (j < c) {
            int rem = c - j;
            u64 ed[8];
#pragma unroll
            for (int i = 0; i < 8; ++i) ed[i] = ev[s + j + i];
            unsigned int cm[8]; float vm[8];
#pragma unroll
            for (int i = 0; i < 8; ++i) {
                bool ok = i < rem;
                cm[i] = ok ? (unsigned int)ed[i] : 0u;
                vm[i] = ok ? __builtin_bit_cast(float, (unsigned int)(ed[i] >> 32)) : 0.f;
            }
            uint2 t[8];
#pragma unroll
            for (int i = 0; i < 8; ++i)
                t[i] = *(const uint2*)(tb + (cm[i] << 9) + coff);
#pragma unroll
            for (int i = 0; i < 8; ++i) {
                a0 += vm[i] * bfl(t[i].x); a1 += vm[i] * bfh(t[i].x);
                a2 += vm[i] * bfl(t[i].y); a3 += vm[i] * bfh(t[i].y);
            }
        }
        size_t moff = (size_t)(mb0 + lr) * 512 + coff;
        u64 o = __builtin_nontemporal_load((const u64*)((const char*)T2 + moff));
        unsigned int ox = (unsigned int)o, oy = (unsigned int)(o >> 32);
        a0 = 2.f * a0 - bfl(ox); a1 = 2.f * a1 - bfh(ox);
        a2 = 2.f * a2 - bfl(oy); a3 = 2.f * a3 - bfh(oy);
        uint2 rr;
        rr.x = pk(a0, a1); rr.y = pk(a2, a3);
        unsigned int swz = coff ^ (((unsigned int)lr & 7u) << 4);
        *(uint2*)((char*)sT4 + lr * 512 + swz) = rr;
    }
    __syncthreads();

    // ---- phase B: out[n, mb0+0..63, :] = bias + sum_k T_k @ W_k ----
    int lrow = l & 15;           // A's m-offset AND C's column f
    int quad = l >> 4;
    float b0 = bias[lrow];
    float b1 = bias[16 + lrow];
    const unsigned short* Ts[4] = {T0, T1, T2, T3};

    for (int tt = w; tt < 32; tt += 16) {        // 32 tasks: (n, 16-row group)
        int n  = tt & 7;
        int rg = tt >> 3;
        int m0l = rg * 16;
        int m0  = mb0 + m0l;
        size_t abase = (size_t)(m0 + lrow) * ROWLEN + quad * 8 + n * FIN;
        f32x4 c0 = {0.f, 0.f, 0.f, 0.f};
        f32x4 c1 = {0.f, 0.f, 0.f, 0.f};
#pragma unroll
        for (int k = 0; k < 4; ++k) {
            short8 a  = *(const short8*)(Ts[k] + abase);
            short8 f0 = *(const short8*)(Wb + ((size_t)(k * 2 + 0) * 64 + l) * 8);
            short8 f1 = *(const short8*)(Wb + ((size_t)(k * 2 + 1) * 64 + l) * 8);
            c0 = __builtin_amdgcn_mfma_f32_16x16x32_bf16(a, f0, c0, 0, 0, 0);
            c1 = __builtin_amdgcn_mfma_f32_16x16x32_bf16(a, f1, c1, 0, 0, 0);
        }
        {   // k = 4 from LDS (swizzled read matches swizzled write, same row)
            int rloc = m0l + lrow;
            unsigned int boff = ((unsigned int)(n * 64 + quad * 16))
                              ^ (((unsigned int)rloc & 7u) << 4);
            short8 a  = *(const short8*)((const char*)sT4 + rloc * 512 + boff);
            short8 f0 = *(const short8*)(Wb + ((size_t)(8) * 64 + l) * 8);
            short8 f1 = *(const short8*)(Wb + ((size_t)(9) * 64 + l) * 8);
            c0 = __builtin_amdgcn_mfma_f32_16x16x32_bf16(a, f0, c0, 0, 0, 0);
            c1 = __builtin_amdgcn_mfma_f32_16x16x32_bf16(a, f1, c1, 0, 0, 0);
        }
        float* op = out + ((size_t)n * M_VERT + m0) * FILT;
#pragma unroll
        for (int r = 0; r < 4; ++r) {
            int orow = quad * 4 + r;
            __builtin_nontemporal_store(c0[r] + b0, &op[(size_t)orow * FILT + lrow]);
            __builtin_nontemporal_store(c1[r] + b1, &op[(size_t)orow * FILT + 16 + lrow]);
        }
    }
}

// ---------------- launch ----------------

extern "C" void kernel_launch(void* const* d_in, const int* in_sizes, int n_in,
                              void* d_out, int out_size, void* d_ws, size_t ws_size,
                              hipStream_t stream) {
    const float* x    = (const float*)d_in[0];
    const float* vals = (const float*)d_in[1];
    const float* W    = (const float*)d_in[2];
    const float* bias = (const float*)d_in[3];
    const int*   rows = (const int*)d_in[4];
    const int*   cols = (const int*)d_in[5];
    float* out = (float*)d_out;

    // workspace: 4 bf16 T buffers (16 MiB each; T4 lives in LDS) + fill + ev + Wb
    const size_t TSZ = (size_t)M_VERT * ROWLEN;
    unsigned short* T0 = (unsigned short*)d_ws;
    unsigned short* T1 = T0 + TSZ;
    unsigned short* T2 = T1 + TSZ;
    unsigned short* T3 = T2 + TSZ;
    int*  fill = (int*)(T3 + TSZ);
    int2* ev   = (int2*)(fill + M_VERT);
    unsigned short* Wb = (unsigned short*)(ev + (size_t)M_VERT * EVROW);

    hipMemsetAsync(fill, 0, M_VERT * sizeof(int), stream);
    pack_kernel<<<M_VERT * 32 / 256, 256, 0, stream>>>(x, T0, rows, cols, vals,
                                                       fill, ev, W, Wb);

    // Chebyshev recurrence (bf16); T4 is produced inside the fused final kernel
    const u64* evq = (const u64*)ev;
    spmm_kernel<<<M_VERT / 4, 256, 0, stream>>>(fill, evq, T0, T0, T1, 0);
    spmm_kernel<<<M_VERT / 4, 256, 0, stream>>>(fill, evq, T1, T0, T2, 1);
    spmm_kernel<<<M_VERT / 4, 256, 0, stream>>>(fill, evq, T2, T1, T3, 1);

    // fused: T4 = 2*L*T3 - T2 (LDS-only) + epilogue GEMM
    spmm4_gemm_kernel<<<M_VERT / 64, 1024, 0, stream>>>(fill, evq, T0, T1, T2, T3,
                                                        Wb, bias, out);
}

// Round 11
// 215.473 us; speedup vs baseline: 3.6500x; 1.0599x over previous
//
#include <hip/hip_runtime.h>

#define M_VERT 32768
#define NBATCH 8
#define FIN 32
#define RANK 5
#define FILT 32
#define E_NNZ 262144
#define ROWLEN 256                    // NBATCH*FIN elements per vertex row
#define EVROW 40                      // fixed ev slots per row (P(cnt>40) ~ 1e-16), mult of 8

typedef short short8 __attribute__((ext_vector_type(8)));
typedef float f32x4 __attribute__((ext_vector_type(4)));
typedef unsigned long long u64;

__device__ __forceinline__ float bfl(unsigned int u) {           // low bf16 -> f32
    unsigned int x = u << 16; return __builtin_bit_cast(float, x);
}
__device__ __forceinline__ float bfh(unsigned int u) {           // high bf16 -> f32
    unsigned int x = u & 0xffff0000u; return __builtin_bit_cast(float, x);
}
__device__ __forceinline__ unsigned int f2bf(float f) {          // f32 -> bf16 (RNE)
    unsigned int x = __builtin_bit_cast(unsigned int, f);
    return (x + 0x7fffu + ((x >> 16) & 1u)) >> 16;
}
__device__ __forceinline__ unsigned int pk(float a, float b) {
    return f2bf(a) | (f2bf(b) << 16);
}

// ---------------- pack x -> T0 bf16 + CSR build + packw (R6/R10-proven) ----------------

__global__ void pack_kernel(const float* __restrict__ x, unsigned short* __restrict__ T0,
                            const int* __restrict__ rows, const int* __restrict__ cols,
                            const float* __restrict__ vals,
                            int* __restrict__ fill, int2* __restrict__ ev,
                            const float* __restrict__ W, unsigned short* __restrict__ Wb) {
    int tid = blockIdx.x * blockDim.x + threadIdx.x;   // M*32 threads
    int m = tid >> 5;
    int r = tid & 31;
    int n = r >> 2;
    int q = r & 3;
    const float* src = x + ((size_t)n * M_VERT + m) * FIN + q * 8;
    float4 v0 = *(const float4*)(src);
    float4 v1 = *(const float4*)(src + 4);
    uint4 u;
    u.x = pk(v0.x, v0.y); u.y = pk(v0.z, v0.w);
    u.z = pk(v1.x, v1.y); u.w = pk(v1.z, v1.w);
    *(uint4*)(T0 + (size_t)m * ROWLEN + n * FIN + q * 8) = u;

    if (tid < E_NNZ) {
        int rr = rows[tid];
        int pos = atomicAdd(&fill[rr], 1);
        if (pos < EVROW) {                       // safety clamp (never taken in practice)
            int2 p; p.x = cols[tid]; p.y = __builtin_bit_cast(int, vals[tid]);
            ev[rr * EVROW + pos] = p;
        }
    }

    if (tid < 640) {
        int lane = tid & 63;
        int kf = tid >> 6;
        int k = kf >> 1, ft = kf & 1;
        int f = ft * 16 + (lane & 15);
        int fin0 = (lane >> 4) * 8;
        unsigned short tmp[8];
#pragma unroll
        for (int j = 0; j < 8; ++j)
            tmp[j] = (unsigned short)f2bf(W[((fin0 + j) * RANK + k) * FILT + f]);
        uint4 uw;
        uw.x = (unsigned int)tmp[0] | ((unsigned int)tmp[1] << 16);
        uw.y = (unsigned int)tmp[2] | ((unsigned int)tmp[3] << 16);
        uw.z = (unsigned int)tmp[4] | ((unsigned int)tmp[5] << 16);
        uw.w = (unsigned int)tmp[6] | ((unsigned int)tmp[7] << 16);
        *(uint4*)(Wb + (size_t)tid * 8) = uw;
    }
}

// ---------------- SpMM (bf16): Tout = L*Tin  or  2*L*Tin - Tsub (R10-proven) ----------------
// One wave per vertex; uniform bounds via readfirstlane -> scalar ev loads; 64
// lanes gather the SAME row -> one coalesced 512B transaction per edge; 8
// outstanding gathers. Masked tail -> no ev memset. Measured floor: ~29 us =
// 134 MB scattered-line service at ~4.6 TB/s (L3 tier); MLP-insensitive (R4).

__global__ __launch_bounds__(256) void spmm_kernel(const int* __restrict__ cnt,
                                                   const u64* __restrict__ ev,
                                                   const unsigned short* __restrict__ Tin,
                                                   const unsigned short* __restrict__ Tsub,
                                                   unsigned short* __restrict__ Tout, int cheb) {
    int w = threadIdx.x >> 6;
    int l = threadIdx.x & 63;
    int m = blockIdx.x * 4 + w;
    unsigned int coff = (unsigned int)l * 8u;    // byte offset within 512B row
    int c = __builtin_amdgcn_readfirstlane(cnt[m]);
    if (c > EVROW) c = EVROW;                    // matches scatter clamp
    int s = m * EVROW;
    int cf = c & ~7;
    const char* tb = (const char*)Tin;
    float a0 = 0.f, a1 = 0.f, a2 = 0.f, a3 = 0.f;
    int j = 0;
    for (; j < cf; j += 8) {                     // full 8-packs (no predication)
        u64 ed[8];
#pragma unroll
        for (int i = 0; i < 8; ++i) ed[i] = ev[s + j + i];   // uniform -> scalar loads
        uint2 t[8];
#pragma unroll
        for (int i = 0; i < 8; ++i)
            t[i] = *(const uint2*)(tb + (((unsigned int)ed[i]) << 9) + coff);
#pragma unroll
        for (int i = 0; i < 8; ++i) {
            float v = __builtin_bit_cast(float, (unsigned int)(ed[i] >> 32));
            a0 += v * bfl(t[i].x); a1 += v * bfh(t[i].x);
            a2 += v * bfl(t[i].y); a3 += v * bfh(t[i].y);
        }
    }
    if (j < c) {                                 // masked tail (1..7 real edges)
        int rem = c - j;
        u64 ed[8];
#pragma unroll
        for (int i = 0; i < 8; ++i) ed[i] = ev[s + j + i];   // may read garbage pads
        unsigned int cm[8]; float vm[8];
#pragma unroll
        for (int i = 0; i < 8; ++i) {            // mask BEFORE any deref
            bool ok = i < rem;
            cm[i] = ok ? (unsigned int)ed[i] : 0u;
            vm[i] = ok ? __builtin_bit_cast(float, (unsigned int)(ed[i] >> 32)) : 0.f;
        }
        uint2 t[8];
#pragma unroll
        for (int i = 0; i < 8; ++i)
            t[i] = *(const uint2*)(tb + (cm[i] << 9) + coff);
#pragma unroll
        for (int i = 0; i < 8; ++i) {
            a0 += vm[i] * bfl(t[i].x); a1 += vm[i] * bfh(t[i].x);
            a2 += vm[i] * bfl(t[i].y); a3 += vm[i] * bfh(t[i].y);
        }
    }
    size_t moff = (size_t)m * 512 + coff;
    if (cheb) {
        u64 o = __builtin_nontemporal_load((const u64*)((const char*)Tsub + moff));
        unsigned int ox = (unsigned int)o, oy = (unsigned int)(o >> 32);
        a0 = 2.f * a0 - bfl(ox); a1 = 2.f * a1 - bfh(ox);
        a2 = 2.f * a2 - bfl(oy); a3 = 2.f * a3 - bfh(oy);
    }
    uint2 rr;
    rr.x = pk(a0, a1); rr.y = pk(a2, a3);
    *(uint2*)((char*)Tout + moff) = rr;
}

// ---------------- fused final SpMM + GEMM (overlapped) ----------------
// Block = 1024 threads (16 waves) owns 64 vertices.
// Phase A: wave w computes T4 rows w*4..+3 = 2*L*T3 - T2 into LDS (swizzled);
// the T2 row it reads for the recurrence is ALSO stashed into LDS (sT2) --
// phase B's k=2 then never touches global (-16.8 MB; fixes R10's nt own-goal
// where phase A evicted the exact lines phase B re-read).
// Overlap: k in {0,1,3} gemm (A global loads + 6/10 MFMAs, Wb frags shared by
// the wave's 2 tasks) runs BEFORE __syncthreads -- early-finishing waves issue
// their A-reads while stragglers drain, instead of idling at the barrier
// (R10 counter evidence: fused 56.2 us vs 29+20 parts). Only k=2/k=4 (LDS)
// run post-barrier. Both tasks' accumulators live across the barrier,
// explicitly unrolled (static indexing; ~52 VGPR < 64 cap).

__global__ __launch_bounds__(1024, 8) void spmm4_gemm_kernel(
        const int* __restrict__ cnt, const u64* __restrict__ ev,
        const unsigned short* __restrict__ T0, const unsigned short* __restrict__ T1,
        const unsigned short* __restrict__ T2, const unsigned short* __restrict__ T3,
        const unsigned short* __restrict__ Wb, const float* __restrict__ bias,
        float* __restrict__ out) {
    __shared__ unsigned short sT4[64 * 256];     // 32 KB, swizzled
    __shared__ unsigned short sT2[64 * 256];     // 32 KB, swizzled
    int w = threadIdx.x >> 6;                    // wave 0..15
    int l = threadIdx.x & 63;
    int mb0 = blockIdx.x * 64;
    unsigned int coff = (unsigned int)l * 8u;
    const char* tb = (const char*)T3;            // Tin = T3

    // ---- phase A: T4 rows = 2*L*T3 - T2 -> sT4; raw T2 rows -> sT2 ----
    for (int vi = 0; vi < 4; ++vi) {
        int lr = w * 4 + vi;                     // local row 0..63
        int m = mb0 + lr;
        int c = __builtin_amdgcn_readfirstlane(cnt[m]);
        if (c > EVROW) c = EVROW;
        int s = m * EVROW;
        int cf = c & ~7;
        float a0 = 0.f, a1 = 0.f, a2 = 0.f, a3 = 0.f;
        int j = 0;
        for (; j < cf; j += 8) {
            u64 ed[8];
#pragma unroll
            for (int i = 0; i < 8; ++i) ed[i] = ev[s + j + i];
            uint2 t[8];
#pragma unroll
            for (int i = 0; i < 8; ++i)
                t[i] = *(const uint2*)(tb + (((unsigned int)ed[i]) << 9) + coff);
#pragma unroll
            for (int i = 0; i < 8; ++i) {
                float v = __builtin_bit_cast(float, (unsigned int)(ed[i] >> 32));
                a0 += v * bfl(t[i].x); a1 += v * bfh(t[i].x);
                a2 += v * bfl(t[i].y); a3 += v * bfh(t[i].y);
            }
        }
        if (j < c) {
            int rem = c - j;
            u64 ed[8];
#pragma unroll
            for (int i = 0; i < 8; ++i) ed[i] = ev[s + j + i];
            unsigned int cm[8]; float vm[8];
#pragma unroll
            for (int i = 0; i < 8; ++i) {
                bool ok = i < rem;
                cm[i] = ok ? (unsigned int)ed[i] : 0u;
                vm[i] = ok ? __builtin_bit_cast(float, (unsigned int)(ed[i] >> 32)) : 0.f;
            }
            uint2 t[8];
#pragma unroll
            for (int i = 0; i < 8; ++i)
                t[i] = *(const uint2*)(tb + (cm[i] << 9) + coff);
#pragma unroll
            for (int i = 0; i < 8; ++i) {
                a0 += vm[i] * bfl(t[i].x); a1 += vm[i] * bfh(t[i].x);
                a2 += vm[i] * bfl(t[i].y); a3 += vm[i] * bfh(t[i].y);
            }
        }
        size_t moff = (size_t)(mb0 + lr) * 512 + coff;
        u64 o = *(const u64*)((const char*)T2 + moff);        // cached: reused via sT2
        unsigned int ox = (unsigned int)o, oy = (unsigned int)(o >> 32);
        unsigned int swz = coff ^ (((unsigned int)lr & 7u) << 4);
        *(u64*)((char*)sT2 + lr * 512 + swz) = o;             // stash raw T2 row
        a0 = 2.f * a0 - bfl(ox); a1 = 2.f * a1 - bfh(ox);
        a2 = 2.f * a2 - bfl(oy); a3 = 2.f * a3 - bfh(oy);
        uint2 rr;
        rr.x = pk(a0, a1); rr.y = pk(a2, a3);
        *(uint2*)((char*)sT4 + lr * 512 + swz) = rr;
    }

    // ---- phase B (early, pre-barrier): k in {0,1,3} for both tasks ----
    int lrow = l & 15;           // A's m-offset AND C's column f
    int quad = l >> 4;
    float b0 = bias[lrow];
    float b1 = bias[16 + lrow];

    // task0: tt = w      -> n = w&7, rg = w>>3        (0 or 1)
    // task1: tt = w + 16 -> same n,  rg = 2 + (w>>3)  (2 or 3)
    int n   = w & 7;
    int rg0 = w >> 3;
    int rg1 = 2 + rg0;
    int m0l0 = rg0 * 16, m0l1 = rg1 * 16;
    size_t ab0 = (size_t)(mb0 + m0l0 + lrow) * ROWLEN + quad * 8 + n * FIN;
    size_t ab1 = (size_t)(mb0 + m0l1 + lrow) * ROWLEN + quad * 8 + n * FIN;

    f32x4 c00 = {0.f, 0.f, 0.f, 0.f};   // task0, filt 0-15
    f32x4 c01 = {0.f, 0.f, 0.f, 0.f};   // task0, filt 16-31
    f32x4 c10 = {0.f, 0.f, 0.f, 0.f};   // task1, filt 0-15
    f32x4 c11 = {0.f, 0.f, 0.f, 0.f};   // task1, filt 16-31

    const unsigned short* TsG[3] = {T0, T1, T3};
    const int kgl[3] = {0, 1, 3};
#pragma unroll
    for (int ki = 0; ki < 3; ++ki) {
        int k = kgl[ki];
        short8 f0 = *(const short8*)(Wb + ((size_t)(k * 2 + 0) * 64 + l) * 8);
        short8 f1 = *(const short8*)(Wb + ((size_t)(k * 2 + 1) * 64 + l) * 8);
        short8 aA = *(const short8*)(TsG[ki] + ab0);
        short8 aB = *(const short8*)(TsG[ki] + ab1);
        c00 = __builtin_amdgcn_mfma_f32_16x16x32_bf16(aA, f0, c00, 0, 0, 0);
        c01 = __builtin_amdgcn_mfma_f32_16x16x32_bf16(aA, f1, c01, 0, 0, 0);
        c10 = __builtin_amdgcn_mfma_f32_16x16x32_bf16(aB, f0, c10, 0, 0, 0);
        c11 = __builtin_amdgcn_mfma_f32_16x16x32_bf16(aB, f1, c11, 0, 0, 0);
    }

    __syncthreads();

    // ---- phase B (late, post-barrier): k=2 (sT2) and k=4 (sT4) ----
    {
        int rl0 = m0l0 + lrow;
        int rl1 = m0l1 + lrow;
        unsigned int bo0 = ((unsigned int)(n * 64 + quad * 16))
                         ^ (((unsigned int)rl0 & 7u) << 4);
        unsigned int bo1 = ((unsigned int)(n * 64 + quad * 16))
                         ^ (((unsigned int)rl1 & 7u) << 4);
        short8 f20 = *(const short8*)(Wb + ((size_t)4 * 64 + l) * 8);
        short8 f21 = *(const short8*)(Wb + ((size_t)5 * 64 + l) * 8);
        short8 f40 = *(const short8*)(Wb + ((size_t)8 * 64 + l) * 8);
        short8 f41 = *(const short8*)(Wb + ((size_t)9 * 64 + l) * 8);

        short8 a2A = *(const short8*)((const char*)sT2 + rl0 * 512 + bo0);
        short8 a2B = *(const short8*)((const char*)sT2 + rl1 * 512 + bo1);
        c00 = __builtin_amdgcn_mfma_f32_16x16x32_bf16(a2A, f20, c00, 0, 0, 0);
        c01 = __builtin_amdgcn_mfma_f32_16x16x32_bf16(a2A, f21, c01, 0, 0, 0);
        c10 = __builtin_amdgcn_mfma_f32_16x16x32_bf16(a2B, f20, c10, 0, 0, 0);
        c11 = __builtin_amdgcn_mfma_f32_16x16x32_bf16(a2B, f21, c11, 0, 0, 0);

        short8 a4A = *(const short8*)((const char*)sT4 + rl0 * 512 + bo0);
        short8 a4B = *(const short8*)((const char*)sT4 + rl1 * 512 + bo1);
        c00 = __builtin_amdgcn_mfma_f32_16x16x32_bf16(a4A, f40, c00, 0, 0, 0);
        c01 = __builtin_amdgcn_mfma_f32_16x16x32_bf16(a4A, f41, c01, 0, 0, 0);
        c10 = __builtin_amdgcn_mfma_f32_16x16x32_bf16(a4B, f40, c10, 0, 0, 0);
        c11 = __builtin_amdgcn_mfma_f32_16x16x32_bf16(a4B, f41, c11, 0, 0, 0);
    }

    // ---- epilogue: bias + nt store ----
    {
        float* op0 = out + ((size_t)n * M_VERT + (mb0 + m0l0)) * FILT;
        float* op1 = out + ((size_t)n * M_VERT + (mb0 + m0l1)) * FILT;
#pragma unroll
        for (int r = 0; r < 4; ++r) {
            int orow = quad * 4 + r;
            __builtin_nontemporal_store(c00[r] + b0, &op0[(size_t)orow * FILT + lrow]);
            __builtin_nontemporal_store(c01[r] + b1, &op0[(size_t)orow * FILT + 16 + lrow]);
            __builtin_nontemporal_store(c10[r] + b0, &op1[(size_t)orow * FILT + lrow]);
            __builtin_nontemporal_store(c11[r] + b1, &op1[(size_t)orow * FILT + 16 + lrow]);
        }
    }
}

// ---------------- launch ----------------

extern "C" void kernel_launch(void* const* d_in, const int* in_sizes, int n_in,
                              void* d_out, int out_size, void* d_ws, size_t ws_size,
                              hipStream_t stream) {
    const float* x    = (const float*)d_in[0];
    const float* vals = (const float*)d_in[1];
    const float* W    = (const float*)d_in[2];
    const float* bias = (const float*)d_in[3];
    const int*   rows = (const int*)d_in[4];
    const int*   cols = (const int*)d_in[5];
    float* out = (float*)d_out;

    // workspace: 4 bf16 T buffers (16 MiB each; T4 lives in LDS) + fill + ev + Wb
    const size_t TSZ = (size_t)M_VERT * ROWLEN;
    unsigned short* T0 = (unsigned short*)d_ws;
    unsigned short* T1 = T0 + TSZ;
    unsigned short* T2 = T1 + TSZ;
    unsigned short* T3 = T2 + TSZ;
    int*  fill = (int*)(T3 + TSZ);
    int2* ev   = (int2*)(fill + M_VERT);
    unsigned short* Wb = (unsigned short*)(ev + (size_t)M_VERT * EVROW);

    hipMemsetAsync(fill, 0, M_VERT * sizeof(int), stream);
    pack_kernel<<<M_VERT * 32 / 256, 256, 0, stream>>>(x, T0, rows, cols, vals,
                                                       fill, ev, W, Wb);

    // Chebyshev recurrence (bf16); T4 is produced inside the fused final kernel
    const u64* evq = (const u64*)ev;
    spmm_kernel<<<M_VERT / 4, 256, 0, stream>>>(fill, evq, T0, T0, T1, 0);
    spmm_kernel<<<M_VERT / 4, 256, 0, stream>>>(fill, evq, T1, T0, T2, 1);
    spmm_kernel<<<M_VERT / 4, 256, 0, stream>>>(fill, evq, T2, T1, T3, 1);

    // fused: T4 = 2*L*T3 - T2 (LDS-only) + overlapped epilogue GEMM
    spmm4_gemm_kernel<<<M_VERT / 64, 1024, 0, stream>>>(fill, evq, T0, T1, T2, T3,
                                                        Wb, bias, out);
}